// Round 11
// baseline (272.234 us; speedup 1.0000x reference)
//
#include <hip/hip_runtime.h>
#include <hip/hip_bf16.h>

// tRNN fused: L1-from-global-gather -> 5 LDS tree levels (MFMA bf16) -> cpr -> softmax
// R11: 2 batch rows per block (ILP fill), no leaf staging: L1 B-frags gathered
//      straight from bf16 voc table (L2-resident). LDS 32KB = 4 trees x 8KB L1-out.
//      Tail levels pack 4 trees into single tiles. 256 thr, launch_bounds(256,4).
// B=8192, SIDES=2, L=64, V=10000, D=128, C=128, R=7

typedef __attribute__((ext_vector_type(8))) short bf16x8;
typedef __attribute__((ext_vector_type(4))) float f32x4;

#define VOCN (10000 * 128)
#define CPSN (128 * 256)
#define CPRN (128 * 256)

__device__ __forceinline__ uint pk2(float a, float b) {
  union { __hip_bfloat162 h2; uint u; } cv;
  cv.h2 = __float22bfloat162_rn(make_float2(a, b));
  return cv.u;
}
__device__ __forceinline__ float2 up2(uint u) {
  union { uint u; __hip_bfloat162 h2; } cv; cv.u = u;
  return __bfloat1622float2(cv.h2);
}
// Odd-polynomial tanh: |err| < 5e-5 for |x| <= 0.6 (pre-acts bounded ~0.5 here).
__device__ __forceinline__ float fast_tanh(float x) {
  const float t = x * x;
  float u = __builtin_fmaf(t, -0.05396825397f, 0.13333333333f);
  u = __builtin_fmaf(t, u, -0.33333333333f);
  u = __builtin_fmaf(t, u, 1.0f);
  return x * u;
}
__device__ __forceinline__ int sf(int r) { return r ^ ((r >> 3) & 7); }   // slot swizzle

// ---- prep: f32 -> bf16 (voc fused with bias) into d_ws ----
__global__ void prep_kernel(const float* __restrict__ voc_w, const float* __restrict__ voc_b,
                            const float* __restrict__ cps_w, const float* __restrict__ cpr_w,
                            ushort* __restrict__ ws) {
  const int i4 = (blockIdx.x * 256 + threadIdx.x) * 4;
  if (i4 >= VOCN + CPSN + CPRN) return;
  float4 v;
  if (i4 < VOCN) {
    v = *(const float4*)(voc_w + i4);
    const float4 bb = *(const float4*)(voc_b + (i4 & 127));
    v.x += bb.x; v.y += bb.y; v.z += bb.z; v.w += bb.w;
  } else if (i4 < VOCN + CPSN) {
    v = *(const float4*)(cps_w + (i4 - VOCN));
  } else {
    v = *(const float4*)(cpr_w + (i4 - VOCN - CPSN));
  }
  uint2 w; w.x = pk2(v.x, v.y); w.y = pk2(v.z, v.w);
  *(uint2*)(ws + i4) = w;
}

// LDS: 2 rows x 16KB. Per row: 16 chunks x 1024B; chunk holds 64 slots x 16B
// (tree t slot s -> physical slot t*32+s, sf-swizzled). Elem k of slot S at byte
// row*16384 + (k>>3)*1024 + sf(S)*16 + (k&7)*2.
#define MFMA16(Ax, Bx, Cx) __builtin_amdgcn_mfma_f32_16x16x32_bf16(Ax, Bx, Cx, 0, 0, 0)

template<int ROFF>
__device__ __forceinline__ void tile16(const char* hb, const bf16x8 (&A)[2][8],
                                       int RL, int RR, f32x4& aA, f32x4& aB) {
  bf16x8 bl[4], br[4];
#pragma unroll
  for (int q = 0; q < 4; ++q) {
    bl[q] = *(const bf16x8*)(hb + RL + ROFF + q * 4096);
    br[q] = *(const bf16x8*)(hb + RR + ROFF + q * 4096);
  }
#pragma unroll
  for (int q = 0; q < 4; ++q) {
    aA = MFMA16(A[0][q], bl[q], aA);
    aB = MFMA16(A[1][q], bl[q], aB);
  }
#pragma unroll
  for (int q = 0; q < 4; ++q) {
    aA = MFMA16(A[0][4 + q], br[q], aA);
    aB = MFMA16(A[1][4 + q], br[q], aB);
  }
}

// L1 tile: B-fragments gathered from global voc table (leaf = voc+bias).
template<int PRE>
__device__ __forceinline__ void gtile(const ushort* __restrict__ voc_bf,
                                      const float* __restrict__ voc_w,
                                      const float* __restrict__ voc_b,
                                      int tok0, int tok1, int lh,
                                      const bf16x8 (&A)[2][8], f32x4& aA, f32x4& aB) {
  bf16x8 bl[4], br[4];
  if constexpr (PRE) {
    const ushort* p0 = voc_bf + tok0 * 128 + lh * 8;
    const ushort* p1 = voc_bf + tok1 * 128 + lh * 8;
#pragma unroll
    for (int q = 0; q < 4; ++q) {
      bl[q] = *(const bf16x8*)(p0 + q * 32);
      br[q] = *(const bf16x8*)(p1 + q * 32);
    }
  } else {
    const float* f0 = voc_w + tok0 * 128 + lh * 8;
    const float* f1 = voc_w + tok1 * 128 + lh * 8;
    const float* fb = voc_b + lh * 8;
#pragma unroll
    for (int q = 0; q < 4; ++q) {
      float4 x0 = *(const float4*)(f0 + q * 32), x1 = *(const float4*)(f0 + q * 32 + 4);
      float4 y0 = *(const float4*)(f1 + q * 32), y1 = *(const float4*)(f1 + q * 32 + 4);
      float4 c0 = *(const float4*)(fb + q * 32), c1 = *(const float4*)(fb + q * 32 + 4);
      union { bf16x8 v; uint4 u; } a, b;
      a.u.x = pk2(x0.x + c0.x, x0.y + c0.y); a.u.y = pk2(x0.z + c0.z, x0.w + c0.w);
      a.u.z = pk2(x1.x + c1.x, x1.y + c1.y); a.u.w = pk2(x1.z + c1.z, x1.w + c1.w);
      b.u.x = pk2(y0.x + c0.x, y0.y + c0.y); b.u.y = pk2(y0.z + c0.z, y0.w + c0.w);
      b.u.z = pk2(y1.x + c1.x, y1.y + c1.y); b.u.w = pk2(y1.z + c1.z, y1.w + c1.w);
      bl[q] = a.v; br[q] = b.v;
    }
  }
#pragma unroll
  for (int q = 0; q < 4; ++q) {
    aA = MFMA16(A[0][q], bl[q], aA);
    aB = MFMA16(A[1][q], bl[q], aB);
  }
#pragma unroll
  for (int q = 0; q < 4; ++q) {
    aA = MFMA16(A[0][4 + q], br[q], aA);
    aB = MFMA16(A[1][4 + q], br[q], aB);
  }
}

template<int ROFF>
__device__ __forceinline__ void wtile(char* hb, int W, const f32x4& aA, const f32x4& aB) {
  uint2 w0, w1;
  w0.x = pk2(fast_tanh(aA[0]), fast_tanh(aA[1]));
  w0.y = pk2(fast_tanh(aA[2]), fast_tanh(aA[3]));
  w1.x = pk2(fast_tanh(aB[0]), fast_tanh(aB[1]));
  w1.y = pk2(fast_tanh(aB[2]), fast_tanh(aB[3]));
  *(uint2*)(hb + W + ROFF) = w0;
  *(uint2*)(hb + W + ROFF + 2048) = w1;
}

template<int PRE>
__global__ __launch_bounds__(256, 4)
void trnn_kernel(const int* __restrict__ tokens,
                 const float* __restrict__ voc_w, const float* __restrict__ voc_b,
                 const float* __restrict__ cps_w, const float* __restrict__ cps_b,
                 const float* __restrict__ cpr_w, const float* __restrict__ cpr_b,
                 const float* __restrict__ sm_w, const float* __restrict__ sm_b,
                 const ushort* __restrict__ wsb, float* __restrict__ out) {
  __shared__ ushort h[16384];      // 32 KB: 2 rows x 16KB (4 trees x 32 slots)
  const int tid = threadIdx.x;
  const int lane = tid & 63, wv = tid >> 6;
  const int l15 = lane & 15, lh = lane >> 4;
  const int b0 = blockIdx.x * 2;
  char* hb = (char*)h;

  const ushort* voc_bf = wsb;
  const ushort* cps_bf = wsb + VOCN;
  const ushort* cpr_bf = wsb + VOCN + CPSN;

  // ---- per-lane LDS bases (row offset 0/16384 added via template imm) ----
  const int lhb = lh * 1024;
  const int dpart = (((wv * 32 + lh * 4) >> 3) << 10) + ((lh & 1) << 3);
  // L1/L2 write (slots t*32 + p*16 + l15)
  const int Wa0 = sf(l15) * 16 + dpart;          // t0 p0 (also L2 out t0)
  const int Wb0 = sf(16 + l15) * 16 + dpart;     // t0 p1
  const int Wa1 = sf(32 + l15) * 16 + dpart;     // t1 p0 (also L2 out t1)
  const int Wb1 = sf(48 + l15) * 16 + dpart;     // t1 p1
  // L2 reads (children 2i,2i+1 of node i=l15, per tree)
  const int R2L0 = lhb + sf(2 * l15) * 16;
  const int R2R0 = lhb + sf(2 * l15 + 1) * 16;
  const int R2L1 = lhb + sf(32 + 2 * l15) * 16;
  const int R2R1 = lhb + sf(33 + 2 * l15) * 16;
  // L3 (per row, trees packed): col l15: tree=(l15>>3), i=l15&7
  const int c3 = ((l15 >> 3) & 1) * 32 + (l15 & 7) * 2;
  const int R3L = lhb + sf(c3) * 16;
  const int R3R = lhb + sf(c3 + 1) * 16;
  const int W3 = sf(((l15 >> 3) & 1) * 32 + (l15 & 7)) * 16 + dpart;
  // L4 (rows+trees packed): row=(l15>>3), tree=(l15>>2)&1, i=l15&3
  const int ro4 = ((l15 >> 3) & 1) << 14;
  const int c4 = ((l15 >> 2) & 1) * 32 + (l15 & 3) * 2;
  const int R4L = ro4 + lhb + sf(c4) * 16;
  const int R4R = ro4 + lhb + sf(c4 + 1) * 16;
  const int W4 = ro4 + sf(((l15 >> 2) & 1) * 32 + (l15 & 3)) * 16 + dpart;
  // L5: row=(l15>>2)&1, tree=(l15>>1)&1, i=l15&1 (valid l15<8)
  const int ro5 = ((l15 >> 2) & 1) << 14;
  const int c5 = ((l15 >> 1) & 1) * 32 + (l15 & 1) * 2;
  const int R5L = ro5 + lhb + sf(c5) * 16;
  const int R5R = ro5 + lhb + sf(c5 + 1) * 16;
  const int W5 = ro5 + sf(((l15 >> 1) & 1) * 32 + (l15 & 1)) * 16 + dpart;
  // L6: row=(l15>>1)&1, tree=l15&1 (valid l15<4); root written in-place at slot t*32
  const int ro6 = ((l15 >> 1) & 1) << 14;
  const int c6 = (l15 & 1) * 32;
  const int R6L = ro6 + lhb + sf(c6) * 16;
  const int R6R = ro6 + lhb + sf(c6 + 1) * 16;
  const int W6 = ro6 + sf((l15 & 1) * 32) * 16 + dpart;

  // ---- cps weights -> A fragments; biases -> regs ----
  bf16x8 A[2][8];
  f32x4 bias[2];
#pragma unroll
  for (int mt = 0; mt < 2; ++mt) {
    const int d = wv * 32 + mt * 16 + l15;
#pragma unroll
    for (int kt = 0; kt < 8; ++kt) {
      const int k = kt * 32 + lh * 8;
      if constexpr (PRE) {
        A[mt][kt] = *(const bf16x8*)(cps_bf + d * 256 + k);
      } else {
        const float* p = cps_w + d * 256 + k;
        float4 lo = *(const float4*)p, hi = *(const float4*)(p + 4);
        union { bf16x8 v; uint4 u; } f;
        f.u.x = pk2(lo.x, lo.y); f.u.y = pk2(lo.z, lo.w);
        f.u.z = pk2(hi.x, hi.y); f.u.w = pk2(hi.z, hi.w);
        A[mt][kt] = f.v;
      }
    }
    const float4 bb = *(const float4*)(cps_b + wv * 32 + mt * 16 + lh * 4);
    bias[mt][0] = bb.x; bias[mt][1] = bb.y; bias[mt][2] = bb.z; bias[mt][3] = bb.w;
  }

  // ---- tokens for this block's 2 rows (tiny region -> L1-cached) ----
  const int* tr0 = tokens + b0 * 128;
  const int* tr1 = tr0 + 128;
  const int e = 2 * l15;
  const int k00a0 = tr0[e],      k00a1 = tr0[e + 1];
  const int k00b0 = tr0[32 + e], k00b1 = tr0[33 + e];
  const int k01a0 = tr0[64 + e], k01a1 = tr0[65 + e];
  const int k01b0 = tr0[96 + e], k01b1 = tr0[97 + e];
  const int k10a0 = tr1[e],      k10a1 = tr1[e + 1];
  const int k10b0 = tr1[32 + e], k10b1 = tr1[33 + e];
  const int k11a0 = tr1[64 + e], k11a1 = tr1[65 + e];
  const int k11b0 = tr1[96 + e], k11b1 = tr1[97 + e];

  // ---- Level 1: leaves gathered from global -> L1-out slots (no LDS reads) ----
  {
    f32x4 aA, aB;
    aA = bias[0]; aB = bias[1];
    gtile<PRE>(voc_bf, voc_w, voc_b, k00a0, k00a1, lh, A, aA, aB);
    wtile<0>(hb, Wa0, aA, aB);
    aA = bias[0]; aB = bias[1];
    gtile<PRE>(voc_bf, voc_w, voc_b, k00b0, k00b1, lh, A, aA, aB);
    wtile<0>(hb, Wb0, aA, aB);
    aA = bias[0]; aB = bias[1];
    gtile<PRE>(voc_bf, voc_w, voc_b, k01a0, k01a1, lh, A, aA, aB);
    wtile<0>(hb, Wa1, aA, aB);
    aA = bias[0]; aB = bias[1];
    gtile<PRE>(voc_bf, voc_w, voc_b, k01b0, k01b1, lh, A, aA, aB);
    wtile<0>(hb, Wb1, aA, aB);
    aA = bias[0]; aB = bias[1];
    gtile<PRE>(voc_bf, voc_w, voc_b, k10a0, k10a1, lh, A, aA, aB);
    wtile<16384>(hb, Wa0, aA, aB);
    aA = bias[0]; aB = bias[1];
    gtile<PRE>(voc_bf, voc_w, voc_b, k10b0, k10b1, lh, A, aA, aB);
    wtile<16384>(hb, Wb0, aA, aB);
    aA = bias[0]; aB = bias[1];
    gtile<PRE>(voc_bf, voc_w, voc_b, k11a0, k11a1, lh, A, aA, aB);
    wtile<16384>(hb, Wa1, aA, aB);
    aA = bias[0]; aB = bias[1];
    gtile<PRE>(voc_bf, voc_w, voc_b, k11b0, k11b1, lh, A, aA, aB);
    wtile<16384>(hb, Wb1, aA, aB);
  }
  __syncthreads();

  // ---- Level 2: 32 -> 16 per tree (4 tiles: 2 rows x 2 trees) ----
  {
    f32x4 a0 = bias[0], b0 = bias[1], a1 = bias[0], b1 = bias[1];
    f32x4 a2 = bias[0], b2 = bias[1], a3 = bias[0], b3 = bias[1];
    tile16<0>(hb, A, R2L0, R2R0, a0, b0);
    tile16<0>(hb, A, R2L1, R2R1, a1, b1);
    tile16<16384>(hb, A, R2L0, R2R0, a2, b2);
    tile16<16384>(hb, A, R2L1, R2R1, a3, b3);
    __syncthreads();
    wtile<0>(hb, Wa0, a0, b0);
    wtile<0>(hb, Wa1, a1, b1);
    wtile<16384>(hb, Wa0, a2, b2);
    wtile<16384>(hb, Wa1, a3, b3);
    __syncthreads();
  }
  // ---- Level 3: 16 -> 8 per tree (2 tiles: rows; trees packed in cols) ----
  {
    f32x4 a0 = bias[0], b0 = bias[1], a1 = bias[0], b1 = bias[1];
    tile16<0>(hb, A, R3L, R3R, a0, b0);
    tile16<16384>(hb, A, R3L, R3R, a1, b1);
    __syncthreads();
    wtile<0>(hb, W3, a0, b0);
    wtile<16384>(hb, W3, a1, b1);
    __syncthreads();
  }
  // ---- Level 4: 8 -> 4 per tree (1 tile: rows+trees packed, all 16 cols) ----
  {
    f32x4 a0 = bias[0], b0 = bias[1];
    tile16<0>(hb, A, R4L, R4R, a0, b0);
    __syncthreads();
    wtile<0>(hb, W4, a0, b0);
    __syncthreads();
  }
  // ---- Level 5: 4 -> 2 per tree (1 tile, 8 valid cols) ----
  {
    f32x4 a0 = bias[0], b0 = bias[1];
    tile16<0>(hb, A, R5L, R5R, a0, b0);
    __syncthreads();
    if (l15 < 8) wtile<0>(hb, W5, a0, b0);
    __syncthreads();
  }
  // ---- Level 6: 2 -> 1 root per tree (1 tile, 4 valid cols) ----
  {
    f32x4 a0 = bias[0], b0 = bias[1];
    tile16<0>(hb, A, R6L, R6R, a0, b0);
    __syncthreads();
    if (l15 < 4) wtile<0>(hb, W6, a0, b0);
    __syncthreads();
  }

  // Roots: row r tree t at byte r*16384 + ch*1024 + sf(t*32)*16 (= 0 / 576).
  // Dead bytes 256-511 of each chunk (slots 16-31) carve zbuf:
  //   z[r][c] at r*16384 + (c>>3)*1024 + 384 + (c&7)*4.

  // ---- cpr: 1 thread per (row, c), full K=256 ----
  {
    const int r = tid >> 7, c = tid & 127;
    const char* rp = hb + r * 16384;
    float acc = 0.f;
#pragma unroll
    for (int t = 0; t < 2; ++t) {
      const int ro = t * 576;
#pragma unroll 4
      for (int ch = 0; ch < 16; ++ch) {
        uint4 u = *(const uint4*)(rp + ch * 1024 + ro);
        float2 e0 = up2(u.x), e1 = up2(u.y), e2 = up2(u.z), e3 = up2(u.w);
        if constexpr (PRE) {
          uint4 wq = *(const uint4*)(cpr_bf + c * 256 + t * 128 + ch * 8);
          float2 w0 = up2(wq.x), w1 = up2(wq.y), w2 = up2(wq.z), w3 = up2(wq.w);
          acc += e0.x * w0.x + e0.y * w0.y + e1.x * w1.x + e1.y * w1.y
               + e2.x * w2.x + e2.y * w2.y + e3.x * w3.x + e3.y * w3.y;
        } else {
          const float* wr = cpr_w + c * 256 + t * 128 + ch * 8;
          float4 w0 = *(const float4*)wr, w1 = *(const float4*)(wr + 4);
          acc += e0.x * w0.x + e0.y * w0.y + e1.x * w0.z + e1.y * w0.w
               + e2.x * w1.x + e2.y * w1.y + e3.x * w1.z + e3.y * w1.w;
        }
      }
    }
    float z = acc + cpr_b[c];
    z = z > 0.f ? z : 0.01f * z;
    *(float*)(hb + r * 16384 + ((c >> 3) << 10) + 384 + ((c & 7) << 2)) = z;
  }
  __syncthreads();

  // ---- softmax: wave 0 -> row 0, wave 1 -> row 1 ----
  if (wv < 2) {
    const char* zb = hb + wv * 16384;
    const int i1 = 64 + lane;
    const float za = *(const float*)(zb + ((lane >> 3) << 10) + 384 + ((lane & 7) << 2));
    const float zc = *(const float*)(zb + ((i1 >> 3) << 10) + 384 + ((i1 & 7) << 2));
    float p[7];
#pragma unroll
    for (int j = 0; j < 7; ++j)
      p[j] = za * sm_w[j * 128 + lane] + zc * sm_w[j * 128 + 64 + lane];
#pragma unroll
    for (int j = 0; j < 7; ++j) {
      float v = p[j];
#pragma unroll
      for (int off = 32; off >= 1; off >>= 1) v += __shfl_xor(v, off, 64);
      p[j] = v + sm_b[j];
    }
    float mx = p[0];
#pragma unroll
    for (int j = 1; j < 7; ++j) mx = fmaxf(mx, p[j]);
    float e2[7], s = 0.f;
#pragma unroll
    for (int j = 0; j < 7; ++j) { e2[j] = __expf(p[j] - mx); s += e2[j]; }
    const float inv = 1.f / s;
    if (lane == 0) {
#pragma unroll
      for (int j = 0; j < 7; ++j) out[(b0 + wv) * 7 + j] = e2[j] * inv;
    }
  }
}

extern "C" void kernel_launch(void* const* d_in, const int* in_sizes, int n_in,
                              void* d_out, int out_size, void* d_ws, size_t ws_size,
                              hipStream_t stream) {
  const int*   tokens = (const int*)  d_in[0];
  const float* voc_w  = (const float*)d_in[1];
  const float* voc_b  = (const float*)d_in[2];
  const float* cps_w  = (const float*)d_in[3];
  const float* cps_b  = (const float*)d_in[4];
  const float* cpr_w  = (const float*)d_in[5];
  const float* cpr_b  = (const float*)d_in[6];
  const float* sm_w   = (const float*)d_in[7];
  const float* sm_b   = (const float*)d_in[8];
  float* out = (float*)d_out;

  const int B = in_sizes[0] / 128;                     // 8192
  const size_t need = (size_t)(VOCN + CPSN + CPRN) * sizeof(ushort);

  if (ws_size >= need) {
    ushort* ws = (ushort*)d_ws;
    const int tot4 = (VOCN + CPSN + CPRN) / 4;
    prep_kernel<<<(tot4 + 255) / 256, 256, 0, stream>>>(voc_w, voc_b, cps_w, cpr_w, ws);
    trnn_kernel<1><<<B / 2, 256, 0, stream>>>(tokens, voc_w, voc_b, cps_w, cps_b,
                                              cpr_w, cpr_b, sm_w, sm_b, ws, out);
  } else {
    trnn_kernel<0><<<B / 2, 256, 0, stream>>>(tokens, voc_w, voc_b, cps_w, cps_b,
                                              cpr_w, cpr_b, sm_w, sm_b,
                                              (const ushort*)d_ws, out);
  }
}

// Round 12
// 196.843 us; speedup vs baseline: 1.3830x; 1.3830x over previous
//
#include <hip/hip_runtime.h>
#include <hip/hip_bf16.h>

// tRNN fused: embedding -> 6 tree levels (MFMA bf16) -> cpr -> softmax
// R12 = R6 structure (256 thr, launch_bounds(256,4), 32KB LDS, imm-offset LDS
//       addressing, exp2 tanh) + 2 batch rows per block sequentially:
//       A-frags/cpr amortized x2, row-1 embed prefetched into regs during
//       row-0 levels, row-0 root stashed in 1 reg/thread -> dead slot 2.
// B=8192, SIDES=2, L=64, V=10000, D=128, C=128, R=7

typedef __attribute__((ext_vector_type(8))) short bf16x8;
typedef __attribute__((ext_vector_type(4))) float f32x4;

#define VOCN (10000 * 128)
#define CPSN (128 * 256)
#define CPRN (128 * 256)

__device__ __forceinline__ uint pk2(float a, float b) {
  union { __hip_bfloat162 h2; uint u; } cv;
  cv.h2 = __float22bfloat162_rn(make_float2(a, b));
  return cv.u;
}
__device__ __forceinline__ float2 up2(uint u) {
  union { uint u; __hip_bfloat162 h2; } cv; cv.u = u;
  return __bfloat1622float2(cv.h2);
}
__device__ __forceinline__ float fast_tanh(float x) {
  float e = __builtin_amdgcn_exp2f(x * 2.88539008f);   // exp(2x)
  return 1.0f - 2.0f * __builtin_amdgcn_rcpf(e + 1.0f);
}
__device__ __forceinline__ int sf(int r) { return r ^ ((r >> 3) & 7); }   // slot swizzle

// ---- prep: f32 -> bf16 (voc fused with bias) into d_ws ----
__global__ void prep_kernel(const float* __restrict__ voc_w, const float* __restrict__ voc_b,
                            const float* __restrict__ cps_w, const float* __restrict__ cpr_w,
                            ushort* __restrict__ ws) {
  const int i4 = (blockIdx.x * 256 + threadIdx.x) * 4;
  if (i4 >= VOCN + CPSN + CPRN) return;
  float4 v;
  if (i4 < VOCN) {
    v = *(const float4*)(voc_w + i4);
    const float4 bb = *(const float4*)(voc_b + (i4 & 127));
    v.x += bb.x; v.y += bb.y; v.z += bb.z; v.w += bb.w;
  } else if (i4 < VOCN + CPSN) {
    v = *(const float4*)(cps_w + (i4 - VOCN));
  } else {
    v = *(const float4*)(cpr_w + (i4 - VOCN - CPSN));
  }
  uint2 w; w.x = pk2(v.x, v.y); w.y = pk2(v.z, v.w);
  *(uint2*)(ws + i4) = w;
}

// LDS layout per tree (16 KB): elem k of slot s at byte
//   (k>>3)*1024 + sf(s)*16 + (k&7)*2 ; tree1 at +16384.
#define MFMA16(Ax, Bx, Cx) __builtin_amdgcn_mfma_f32_16x16x32_bf16(Ax, Bx, Cx, 0, 0, 0)

struct Bases {
  int RLa, RRa, RLb, RRb, RL3, RR3, RL4, RR4, RL5, RR5, RL6, RR6;
  int Wa, Wb, W3, W4, W5, W6;
};

template<int TOFF>
__device__ __forceinline__ void tile16(const char* hb, const bf16x8 (&A)[2][8],
                                       int RL, int RR, f32x4& aA, f32x4& aB) {
  bf16x8 bl[4], br[4];
#pragma unroll
  for (int q = 0; q < 4; ++q) {
    bl[q] = *(const bf16x8*)(hb + RL + TOFF + q * 4096);
    br[q] = *(const bf16x8*)(hb + RR + TOFF + q * 4096);
  }
#pragma unroll
  for (int q = 0; q < 4; ++q) {
    aA = MFMA16(A[0][q], bl[q], aA);
    aB = MFMA16(A[1][q], bl[q], aB);
  }
#pragma unroll
  for (int q = 0; q < 4; ++q) {
    aA = MFMA16(A[0][4 + q], br[q], aA);
    aB = MFMA16(A[1][4 + q], br[q], aB);
  }
}

template<int TOFF>
__device__ __forceinline__ void wtile(char* hb, int W, const f32x4& aA, const f32x4& aB) {
  uint2 w0, w1;
  w0.x = pk2(fast_tanh(aA[0]), fast_tanh(aA[1]));
  w0.y = pk2(fast_tanh(aA[2]), fast_tanh(aA[3]));
  w1.x = pk2(fast_tanh(aB[0]), fast_tanh(aB[1]));
  w1.y = pk2(fast_tanh(aB[2]), fast_tanh(aB[3]));
  *(uint2*)(hb + W + TOFF) = w0;
  *(uint2*)(hb + W + TOFF + 2048) = w1;
}

// 6 levels, R6 structure (in-place slots, 2 barriers per level where needed).
__device__ __forceinline__ void run_levels(char* hb, const bf16x8 (&A)[2][8],
                                           const f32x4 (&bias)[2], const Bases& B,
                                           int l15) {
  // L1: 64 leaves -> 32 nodes/tree (4 tiles)
  {
    f32x4 a0 = bias[0], b0 = bias[1], a1 = bias[0], b1 = bias[1];
    f32x4 a2 = bias[0], b2 = bias[1], a3 = bias[0], b3 = bias[1];
    tile16<0>(hb, A, B.RLa, B.RRa, a0, b0);
    tile16<0>(hb, A, B.RLb, B.RRb, a1, b1);
    tile16<16384>(hb, A, B.RLa, B.RRa, a2, b2);
    tile16<16384>(hb, A, B.RLb, B.RRb, a3, b3);
    __syncthreads();
    wtile<0>(hb, B.Wa, a0, b0);
    wtile<0>(hb, B.Wb, a1, b1);
    wtile<16384>(hb, B.Wa, a2, b2);
    wtile<16384>(hb, B.Wb, a3, b3);
    __syncthreads();
  }
  // L2: 32 -> 16 (2 tiles)
  {
    f32x4 a0 = bias[0], b0 = bias[1], a1 = bias[0], b1 = bias[1];
    tile16<0>(hb, A, B.RLa, B.RRa, a0, b0);
    tile16<16384>(hb, A, B.RLa, B.RRa, a1, b1);
    __syncthreads();
    wtile<0>(hb, B.Wa, a0, b0);
    wtile<16384>(hb, B.Wa, a1, b1);
    __syncthreads();
  }
  // L3: 16 -> 8 (1 tile, trees packed)
  {
    f32x4 a0 = bias[0], b0 = bias[1];
    tile16<0>(hb, A, B.RL3, B.RR3, a0, b0);
    __syncthreads();
    wtile<0>(hb, B.W3, a0, b0);
    __syncthreads();
  }
  // L4: 8 -> 4 (8 valid cols)
  {
    f32x4 a0 = bias[0], b0 = bias[1];
    tile16<0>(hb, A, B.RL4, B.RR4, a0, b0);
    __syncthreads();
    if (l15 < 8) wtile<0>(hb, B.W4, a0, b0);
    __syncthreads();
  }
  // L5: 4 -> 2 (4 valid cols)
  {
    f32x4 a0 = bias[0], b0 = bias[1];
    tile16<0>(hb, A, B.RL5, B.RR5, a0, b0);
    __syncthreads();
    if (l15 < 4) wtile<0>(hb, B.W5, a0, b0);
    __syncthreads();
  }
  // L6: 2 -> 1 root at slot 0 (2 valid cols)
  {
    f32x4 a0 = bias[0], b0 = bias[1];
    tile16<0>(hb, A, B.RL6, B.RR6, a0, b0);
    __syncthreads();
    if (l15 < 2) wtile<0>(hb, B.W6, a0, b0);
    __syncthreads();
  }
}

template<int PRE>
__global__ __launch_bounds__(256, 4)
void trnn_kernel(const int* __restrict__ tokens,
                 const float* __restrict__ voc_w, const float* __restrict__ voc_b,
                 const float* __restrict__ cps_w, const float* __restrict__ cps_b,
                 const float* __restrict__ cpr_w, const float* __restrict__ cpr_b,
                 const float* __restrict__ sm_w, const float* __restrict__ sm_b,
                 const ushort* __restrict__ wsb, float* __restrict__ out) {
  __shared__ ushort h[16384];      // exactly 32 KB: 2 trees x (16 chunks x 64 slots x 16B)
  const int tid = threadIdx.x;
  const int lane = tid & 63, wv = tid >> 6;
  const int l15 = lane & 15, lh = lane >> 4;
  const int b0 = blockIdx.x * 2;
  char* hb = (char*)h;

  const ushort* voc_bf = wsb;
  const ushort* cps_bf = wsb + VOCN;
  const ushort* cpr_bf = wsb + VOCN + CPSN;

  // ---- per-lane LDS address bases (R6 scheme) ----
  Bases Bs;
  {
    const int lhb = lh * 1024;
    Bs.RLa = lhb + sf(2 * l15) * 16;
    Bs.RRa = lhb + sf(2 * l15 + 1) * 16;
    Bs.RLb = lhb + sf(2 * l15 + 32) * 16;
    Bs.RRb = lhb + sf(2 * l15 + 33) * 16;
    Bs.RL3 = (((l15 >> 3) & 1) << 14) + lhb + sf((l15 & 7) * 2) * 16;
    Bs.RR3 = (((l15 >> 3) & 1) << 14) + lhb + sf((l15 & 7) * 2 + 1) * 16;
    Bs.RL4 = (((l15 >> 2) & 1) << 14) + lhb + sf((l15 & 3) * 2) * 16;
    Bs.RR4 = (((l15 >> 2) & 1) << 14) + lhb + sf((l15 & 3) * 2 + 1) * 16;
    Bs.RL5 = (((l15 >> 1) & 1) << 14) + lhb + sf((l15 & 1) * 2) * 16;
    Bs.RR5 = (((l15 >> 1) & 1) << 14) + lhb + sf((l15 & 1) * 2 + 1) * 16;
    Bs.RL6 = ((l15 & 1) << 14) + lhb;            // sf(0)=0
    Bs.RR6 = ((l15 & 1) << 14) + lhb + 16;       // sf(1)=1
    const int dpart = (((wv * 32 + lh * 4) >> 3) << 10) + ((lh & 1) << 3);
    Bs.Wa = sf(l15) * 16 + dpart;
    Bs.Wb = sf(l15 + 16) * 16 + dpart;
    Bs.W3 = (((l15 >> 3) & 1) << 14) + sf(l15 & 7) * 16 + dpart;
    Bs.W4 = (((l15 >> 2) & 1) << 14) + sf(l15 & 3) * 16 + dpart;
    Bs.W5 = (((l15 >> 1) & 1) << 14) + sf(l15 & 1) * 16 + dpart;
    Bs.W6 = ((l15 & 1) << 14) + dpart;           // root -> slot 0
  }

  // ---- cps weights -> A fragments; biases -> regs ----
  bf16x8 A[2][8];
  f32x4 bias[2];
#pragma unroll
  for (int mt = 0; mt < 2; ++mt) {
    const int d = wv * 32 + mt * 16 + l15;
#pragma unroll
    for (int kt = 0; kt < 8; ++kt) {
      const int k = kt * 32 + lh * 8;
      if constexpr (PRE) {
        A[mt][kt] = *(const bf16x8*)(cps_bf + d * 256 + k);
      } else {
        const float* p = cps_w + d * 256 + k;
        float4 lo = *(const float4*)p, hi = *(const float4*)(p + 4);
        union { bf16x8 v; uint4 u; } f;
        f.u.x = pk2(lo.x, lo.y); f.u.y = pk2(lo.z, lo.w);
        f.u.z = pk2(hi.x, hi.y); f.u.w = pk2(hi.z, hi.w);
        A[mt][kt] = f.v;
      }
    }
    const float4 bb = *(const float4*)(cps_b + wv * 32 + mt * 16 + lh * 4);
    bias[mt][0] = bb.x; bias[mt][1] = bb.y; bias[mt][2] = bb.z; bias[mt][3] = bb.w;
  }

  // ---- embedding row 0 + prefetch row 1 into regs ----
  const int tree_e = tid >> 7, lf_e = (tid >> 1) & 63, half_e = tid & 1;
  char* tp = hb + tree_e * 16384 + half_e * 8192 + sf(lf_e) * 16;
  const int tok0 = tokens[b0 * 128 + tree_e * 64 + lf_e];
  const int tok1 = tokens[(b0 + 1) * 128 + tree_e * 64 + lf_e];
  uint4 pf[8];
  if constexpr (PRE) {
    const ushort* vr0 = voc_bf + tok0 * 128 + half_e * 64;
#pragma unroll
    for (int j = 0; j < 8; ++j)
      *(uint4*)(tp + j * 1024) = *(const uint4*)(vr0 + j * 8);
    const ushort* vr1 = voc_bf + tok1 * 128 + half_e * 64;
#pragma unroll
    for (int j = 0; j < 8; ++j)
      pf[j] = *(const uint4*)(vr1 + j * 8);     // in flight across row-0 levels
  } else {
    const float* vw = voc_w + tok0 * 128 + half_e * 64;
    const float* vb = voc_b + half_e * 64;
#pragma unroll
    for (int j = 0; j < 8; ++j) {
      float4 v0 = *(const float4*)(vw + j * 8);
      float4 v1 = *(const float4*)(vw + j * 8 + 4);
      float4 q0 = *(const float4*)(vb + j * 8);
      float4 q1 = *(const float4*)(vb + j * 8 + 4);
      uint4 w;
      w.x = pk2(v0.x + q0.x, v0.y + q0.y);
      w.y = pk2(v0.z + q0.z, v0.w + q0.w);
      w.z = pk2(v1.x + q1.x, v1.y + q1.y);
      w.w = pk2(v1.z + q1.z, v1.w + q1.w);
      *(uint4*)(tp + j * 1024) = w;
    }
  }
  __syncthreads();

  // ---- row 0 levels ----
  run_levels(hb, A, bias, Bs, l15);

  // ---- stash row-0 roots (2 trees x 128 bf16): tid<128 holds 1 uint ----
  uint stash = 0;
  if (tid < 128) {
    const int T = tid >> 6, d2 = tid & 63;
    stash = *(const uint*)(hb + T * 16384 + ((2 * d2) >> 3) * 1024 + ((2 * d2) & 7) * 2);
  }
  __syncthreads();   // stash reads done before row-1 embed overwrites

  // ---- embedding row 1 (from prefetched regs) ----
  if constexpr (PRE) {
#pragma unroll
    for (int j = 0; j < 8; ++j)
      *(uint4*)(tp + j * 1024) = pf[j];
  } else {
    const float* vw = voc_w + tok1 * 128 + half_e * 64;
    const float* vb = voc_b + half_e * 64;
#pragma unroll
    for (int j = 0; j < 8; ++j) {
      float4 v0 = *(const float4*)(vw + j * 8);
      float4 v1 = *(const float4*)(vw + j * 8 + 4);
      float4 q0 = *(const float4*)(vb + j * 8);
      float4 q1 = *(const float4*)(vb + j * 8 + 4);
      uint4 w;
      w.x = pk2(v0.x + q0.x, v0.y + q0.y);
      w.y = pk2(v0.z + q0.z, v0.w + q0.w);
      w.z = pk2(v1.x + q1.x, v1.y + q1.y);
      w.w = pk2(v1.z + q1.z, v1.w + q1.w);
      *(uint4*)(tp + j * 1024) = w;
    }
  }
  __syncthreads();

  // ---- row 1 levels ----
  run_levels(hb, A, bias, Bs, l15);

  // ---- replay row-0 roots into dead slot 2 (bytes 32..47 of each chunk) ----
  if (tid < 128) {
    const int T = tid >> 6, d2 = tid & 63;
    *(uint*)(hb + T * 16384 + ((2 * d2) >> 3) * 1024 + 32 + ((2 * d2) & 7) * 2) = stash;
  }
  __syncthreads();

  // ---- cpr: 1 thread per (row r, output c), full K=256 ----
  // row-0 root at slot 2 (byte +32), row-1 root at slot 0 (byte +0).
  {
    const int r = tid >> 7, c = tid & 127;
    const int rbase = r ? 0 : 32;
    float acc = 0.f;
#pragma unroll
    for (int t = 0; t < 2; ++t) {
#pragma unroll 4
      for (int ch = 0; ch < 16; ++ch) {
        uint4 u = *(const uint4*)(hb + t * 16384 + ch * 1024 + rbase);
        float2 e0 = up2(u.x), e1 = up2(u.y), e2 = up2(u.z), e3 = up2(u.w);
        if constexpr (PRE) {
          uint4 wq = *(const uint4*)(cpr_bf + c * 256 + t * 128 + ch * 8);
          float2 w0 = up2(wq.x), w1 = up2(wq.y), w2 = up2(wq.z), w3 = up2(wq.w);
          acc += e0.x * w0.x + e0.y * w0.y + e1.x * w1.x + e1.y * w1.y
               + e2.x * w2.x + e2.y * w2.y + e3.x * w3.x + e3.y * w3.y;
        } else {
          const float* wr = cpr_w + c * 256 + t * 128 + ch * 8;
          float4 w0 = *(const float4*)wr, w1 = *(const float4*)(wr + 4);
          acc += e0.x * w0.x + e0.y * w0.y + e1.x * w0.z + e1.y * w0.w
               + e2.x * w1.x + e2.y * w1.y + e3.x * w1.z + e3.y * w1.w;
        }
      }
    }
    float z = acc + cpr_b[c];
    z = z > 0.f ? z : 0.01f * z;
    // z[r][c] carved at region r bytes 768..799 of chunk (c>>3)
    *(float*)(hb + r * 16384 + ((c >> 3) << 10) + 768 + ((c & 7) << 2)) = z;
  }
  __syncthreads();

  // ---- softmax: wave 0 -> row 0, wave 1 -> row 1 ----
  if (wv < 2) {
    const char* zb = hb + wv * 16384;
    const int i1 = 64 + lane;
    const float za = *(const float*)(zb + ((lane >> 3) << 10) + 768 + ((lane & 7) << 2));
    const float zc = *(const float*)(zb + ((i1 >> 3) << 10) + 768 + ((i1 & 7) << 2));
    float p[7];
#pragma unroll
    for (int j = 0; j < 7; ++j)
      p[j] = za * sm_w[j * 128 + lane] + zc * sm_w[j * 128 + 64 + lane];
#pragma unroll
    for (int j = 0; j < 7; ++j) {
      float v = p[j];
#pragma unroll
      for (int off = 32; off >= 1; off >>= 1) v += __shfl_xor(v, off, 64);
      p[j] = v + sm_b[j];
    }
    float mx = p[0];
#pragma unroll
    for (int j = 1; j < 7; ++j) mx = fmaxf(mx, p[j]);
    float e[7], s = 0.f;
#pragma unroll
    for (int j = 0; j < 7; ++j) { e[j] = __expf(p[j] - mx); s += e[j]; }
    const float inv = 1.f / s;
    if (lane == 0) {
#pragma unroll
      for (int j = 0; j < 7; ++j) out[(b0 + wv) * 7 + j] = e[j] * inv;
    }
  }
}

extern "C" void kernel_launch(void* const* d_in, const int* in_sizes, int n_in,
                              void* d_out, int out_size, void* d_ws, size_t ws_size,
                              hipStream_t stream) {
  const int*   tokens = (const int*)  d_in[0];
  const float* voc_w  = (const float*)d_in[1];
  const float* voc_b  = (const float*)d_in[2];
  const float* cps_w  = (const float*)d_in[3];
  const float* cps_b  = (const float*)d_in[4];
  const float* cpr_w  = (const float*)d_in[5];
  const float* cpr_b  = (const float*)d_in[6];
  const float* sm_w   = (const float*)d_in[7];
  const float* sm_b   = (const float*)d_in[8];
  float* out = (float*)d_out;

  const int B = in_sizes[0] / 128;                     // 8192
  const size_t need = (size_t)(VOCN + CPSN + CPRN) * sizeof(ushort);

  if (ws_size >= need) {
    ushort* ws = (ushort*)d_ws;
    const int tot4 = (VOCN + CPSN + CPRN) / 4;
    prep_kernel<<<(tot4 + 255) / 256, 256, 0, stream>>>(voc_w, voc_b, cps_w, cpr_w, ws);
    trnn_kernel<1><<<B / 2, 256, 0, stream>>>(tokens, voc_w, voc_b, cps_w, cps_b,
                                              cpr_w, cpr_b, sm_w, sm_b, ws, out);
  } else {
    trnn_kernel<0><<<B / 2, 256, 0, stream>>>(tokens, voc_w, voc_b, cps_w, cps_b,
                                              cpr_w, cpr_b, sm_w, sm_b,
                                              (const ushort*)d_ws, out);
  }
}

// Round 13
// 162.317 us; speedup vs baseline: 1.6772x; 1.2127x over previous
//
#include <hip/hip_runtime.h>
#include <hip/hip_bf16.h>

// tRNN fused: embedding -> 6 tree levels (MFMA bf16) -> cpr -> softmax
// R13 = R6 + conflict-free LDS layout: per-level even/odd slot split
//       (node i -> phys slot (i&1)*H + (i>>1)), making every B-fragment
//       read 16B-stride contiguous across lanes (0 excess bank conflicts).
//       Everything else identical to R6 (256 thr, launch_bounds(256,4),
//       32KB LDS, imm-offset addressing, exp2 tanh).
// B=8192, SIDES=2, L=64, V=10000, D=128, C=128, R=7

typedef __attribute__((ext_vector_type(8))) short bf16x8;
typedef __attribute__((ext_vector_type(4))) float f32x4;

#define VOCN (10000 * 128)
#define CPSN (128 * 256)
#define CPRN (128 * 256)

__device__ __forceinline__ uint pk2(float a, float b) {
  union { __hip_bfloat162 h2; uint u; } cv;
  cv.h2 = __float22bfloat162_rn(make_float2(a, b));
  return cv.u;
}
__device__ __forceinline__ float2 up2(uint u) {
  union { uint u; __hip_bfloat162 h2; } cv; cv.u = u;
  return __bfloat1622float2(cv.h2);
}
__device__ __forceinline__ float fast_tanh(float x) {
  float e = __builtin_amdgcn_exp2f(x * 2.88539008f);   // exp(2x)
  return 1.0f - 2.0f * __builtin_amdgcn_rcpf(e + 1.0f);
}

// ---- prep: f32 -> bf16 (voc fused with bias) into d_ws ----
__global__ void prep_kernel(const float* __restrict__ voc_w, const float* __restrict__ voc_b,
                            const float* __restrict__ cps_w, const float* __restrict__ cpr_w,
                            ushort* __restrict__ ws) {
  const int i4 = (blockIdx.x * 256 + threadIdx.x) * 4;
  if (i4 >= VOCN + CPSN + CPRN) return;
  float4 v;
  if (i4 < VOCN) {
    v = *(const float4*)(voc_w + i4);
    const float4 bb = *(const float4*)(voc_b + (i4 & 127));
    v.x += bb.x; v.y += bb.y; v.z += bb.z; v.w += bb.w;
  } else if (i4 < VOCN + CPSN) {
    v = *(const float4*)(cps_w + (i4 - VOCN));
  } else {
    v = *(const float4*)(cpr_w + (i4 - VOCN - CPSN));
  }
  uint2 w; w.x = pk2(v.x, v.y); w.y = pk2(v.z, v.w);
  *(uint2*)(ws + i4) = w;
}

// LDS layout per tree (16 KB): elem k of PHYS slot s at byte
//   (k>>3)*1024 + s*16 + (k&7)*2 ; tree1 at +16384.  (no XOR swizzle)
// Per-level logical->phys: node i -> (i&1)*H + (i>>1), H = level node count/2
//   => next level's left children are phys 0..H-1, right children H..2H-1
//   => lane-contiguous 16B-stride reads, conflict-free.
#define MFMA16(Ax, Bx, Cx) __builtin_amdgcn_mfma_f32_16x16x32_bf16(Ax, Bx, Cx, 0, 0, 0)

template<int TOFF>
__device__ __forceinline__ void tile16(const char* hb, const bf16x8 (&A)[2][8],
                                       int RL, int RR, f32x4& aA, f32x4& aB) {
  bf16x8 bl[4], br[4];
#pragma unroll
  for (int q = 0; q < 4; ++q) {
    bl[q] = *(const bf16x8*)(hb + RL + TOFF + q * 4096);
    br[q] = *(const bf16x8*)(hb + RR + TOFF + q * 4096);
  }
#pragma unroll
  for (int q = 0; q < 4; ++q) {
    aA = MFMA16(A[0][q], bl[q], aA);
    aB = MFMA16(A[1][q], bl[q], aB);
  }
#pragma unroll
  for (int q = 0; q < 4; ++q) {
    aA = MFMA16(A[0][4 + q], br[q], aA);
    aB = MFMA16(A[1][4 + q], br[q], aB);
  }
}

// W: per-lane write base (phys slot + d-chunk + d-byte); mt1 at +2048.
template<int TOFF>
__device__ __forceinline__ void wtile(char* hb, int W, const f32x4& aA, const f32x4& aB) {
  uint2 w0, w1;
  w0.x = pk2(fast_tanh(aA[0]), fast_tanh(aA[1]));
  w0.y = pk2(fast_tanh(aA[2]), fast_tanh(aA[3]));
  w1.x = pk2(fast_tanh(aB[0]), fast_tanh(aB[1]));
  w1.y = pk2(fast_tanh(aB[2]), fast_tanh(aB[3]));
  *(uint2*)(hb + W + TOFF) = w0;
  *(uint2*)(hb + W + TOFF + 2048) = w1;
}

template<int PRE>
__global__ __launch_bounds__(256, 4)
void trnn_kernel(const int* __restrict__ tokens,
                 const float* __restrict__ voc_w, const float* __restrict__ voc_b,
                 const float* __restrict__ cps_w, const float* __restrict__ cps_b,
                 const float* __restrict__ cpr_w, const float* __restrict__ cpr_b,
                 const float* __restrict__ sm_w, const float* __restrict__ sm_b,
                 const ushort* __restrict__ wsb, float* __restrict__ out) {
  __shared__ ushort h[16384];      // exactly 32 KB: 2 trees x (16 chunks x 64 slots x 16B)
  const int tid = threadIdx.x;
  const int lane = tid & 63, wv = tid >> 6;
  const int l15 = lane & 15, lh = lane >> 4;
  const int b = blockIdx.x;
  char* hb = (char*)h;

  const ushort* voc_bf = wsb;
  const ushort* cps_bf = wsb + VOCN;
  const ushort* cpr_bf = wsb + VOCN + CPSN;

  // ---- per-lane LDS bases (contiguous-slot scheme) ----
  const int lhb = lh * 1024;
  const int lb16 = l15 * 16;
  // Leaves at p(r) = (r&1)*32 + (r>>1):
  //  L1 tile a (nodes 0-15):  left rows 2i   -> slots 0-15,  right -> 32-47
  //  L1 tile b (nodes 16-31): left rows 32+2i-> slots 16-31, right -> 48-63
  const int RLa = lhb + lb16;            // slots  0-15
  const int RLb = lhb + 256 + lb16;      // slots 16-31
  const int RRa = lhb + 512 + lb16;      // slots 32-47
  const int RRb = lhb + 768 + lb16;      // slots 48-63
  // L2 reads L1-out (H=16): left q=l15 (RLa), right q=16+l15 (RLb)
  // L3: trees packed in cols: tree=(l15>>3), j=l15&7; L2-out H=8
  const int t3 = ((l15 >> 3) & 1) << 14;
  const int RL3 = t3 + lhb + (l15 & 7) * 16;          // slots 0-7
  const int RR3 = RL3 + 128;                          // slots 8-15
  // L4: tree=(l15>>2)&1, j=l15&3; L3-out H=4
  const int t4 = ((l15 >> 2) & 1) << 14;
  const int RL4 = t4 + lhb + (l15 & 3) * 16;          // slots 0-3
  const int RR4 = RL4 + 64;                           // slots 4-7
  // L5: tree=(l15>>1)&1, j=l15&1; L4-out H=2
  const int t5 = ((l15 >> 1) & 1) << 14;
  const int RL5 = t5 + lhb + (l15 & 1) * 16;          // slots 0-1
  const int RR5 = RL5 + 32;                           // slots 2-3
  // L6: tree=l15&1; L5-out H=1
  const int t6 = (l15 & 1) << 14;
  const int RL6 = t6 + lhb;                           // slot 0
  const int RR6 = RL6 + 16;                           // slot 1
  // writes: d-part (chunk + byte within 16B slot)
  const int dpart = (((wv * 32 + lh * 4) >> 3) << 10) + ((lh & 1) << 3);
  // L1 out node i -> (i&1)*16 + (i>>1)
  const int Wa = ((l15 & 1) * 16 + (l15 >> 1)) * 16 + dpart;          // nodes 0-15
  const int Wb = Wa + 128;                                            // nodes 16-31 (+8 slots)
  // L2 out node l15 -> (l15&1)*8 + (l15>>1)   (per tree, tree via TOFF)
  const int W2 = ((l15 & 1) * 8 + (l15 >> 1)) * 16 + dpart;
  // L3 out node j of tree -> (j&1)*4 + (j>>1)
  const int W3 = t3 + (((l15 & 1) * 4 + ((l15 & 7) >> 1)) * 16) + dpart;
  // L4 out node j -> (j&1)*2 + (j>>1)   (valid l15<8)
  const int W4 = t4 + (((l15 & 1) * 2 + ((l15 & 3) >> 1)) * 16) + dpart;
  // L5 out node j -> j                  (valid l15<4)
  const int W5 = t5 + ((l15 & 1) * 16) + dpart;
  // L6 root -> slot 0                   (valid l15<2)
  const int W6 = t6 + dpart;

  // ---- cps weights -> A fragments; biases -> regs ----
  bf16x8 A[2][8];
  f32x4 bias[2];
#pragma unroll
  for (int mt = 0; mt < 2; ++mt) {
    const int d = wv * 32 + mt * 16 + l15;
#pragma unroll
    for (int kt = 0; kt < 8; ++kt) {
      const int k = kt * 32 + lh * 8;
      if constexpr (PRE) {
        A[mt][kt] = *(const bf16x8*)(cps_bf + d * 256 + k);
      } else {
        const float* p = cps_w + d * 256 + k;
        float4 lo = *(const float4*)p, hi = *(const float4*)(p + 4);
        union { bf16x8 v; uint4 u; } f;
        f.u.x = pk2(lo.x, lo.y); f.u.y = pk2(lo.z, lo.w);
        f.u.z = pk2(hi.x, hi.y); f.u.w = pk2(hi.z, hi.w);
        A[mt][kt] = f.v;
      }
    }
    const float4 bb = *(const float4*)(cps_b + wv * 32 + mt * 16 + lh * 4);
    bias[mt][0] = bb.x; bias[mt][1] = bb.y; bias[mt][2] = bb.z; bias[mt][3] = bb.w;
  }

  // ---- embedding: 2 threads per (tree, leaf) row; leaf r -> slot (r&1)*32+(r>>1) ----
  {
    const int tree = tid >> 7, lf = (tid >> 1) & 63, half = tid & 1;
    const int tok = tokens[b * 128 + tree * 64 + lf];
    const int p = (lf & 1) * 32 + (lf >> 1);
    char* tp = hb + tree * 16384 + half * 8192 + p * 16;
    if constexpr (PRE) {
      const ushort* vr = voc_bf + tok * 128 + half * 64;
#pragma unroll
      for (int j = 0; j < 8; ++j) {
        const int c = (j + p) & 7;           // rotate chunk start -> spread banks
        *(uint4*)(tp + c * 1024) = *(const uint4*)(vr + c * 8);
      }
    } else {
      const float* vw = voc_w + tok * 128 + half * 64;
      const float* vb = voc_b + half * 64;
#pragma unroll
      for (int j = 0; j < 8; ++j) {
        const int c = (j + p) & 7;
        float4 v0 = *(const float4*)(vw + c * 8);
        float4 v1 = *(const float4*)(vw + c * 8 + 4);
        float4 q0 = *(const float4*)(vb + c * 8);
        float4 q1 = *(const float4*)(vb + c * 8 + 4);
        uint4 w;
        w.x = pk2(v0.x + q0.x, v0.y + q0.y);
        w.y = pk2(v0.z + q0.z, v0.w + q0.w);
        w.z = pk2(v1.x + q1.x, v1.y + q1.y);
        w.w = pk2(v1.z + q1.z, v1.w + q1.w);
        *(uint4*)(tp + c * 1024) = w;
      }
    }
  }
  __syncthreads();

  // ---- Level 1: leaves -> 32 nodes/tree (4 tiles) ----
  {
    f32x4 a0 = bias[0], b0 = bias[1], a1 = bias[0], b1 = bias[1];
    f32x4 a2 = bias[0], b2 = bias[1], a3 = bias[0], b3 = bias[1];
    tile16<0>(hb, A, RLa, RRa, a0, b0);
    tile16<0>(hb, A, RLb, RRb, a1, b1);
    tile16<16384>(hb, A, RLa, RRa, a2, b2);
    tile16<16384>(hb, A, RLb, RRb, a3, b3);
    __syncthreads();
    wtile<0>(hb, Wa, a0, b0);
    wtile<0>(hb, Wb, a1, b1);
    wtile<16384>(hb, Wa, a2, b2);
    wtile<16384>(hb, Wb, a3, b3);
    __syncthreads();
  }
  // ---- Level 2: L1-out (slots 0-31) -> 16 nodes/tree (2 tiles) ----
  {
    f32x4 a0 = bias[0], b0 = bias[1], a1 = bias[0], b1 = bias[1];
    tile16<0>(hb, A, RLa, RLb, a0, b0);
    tile16<16384>(hb, A, RLa, RLb, a1, b1);
    __syncthreads();
    wtile<0>(hb, W2, a0, b0);
    wtile<16384>(hb, W2, a1, b1);
    __syncthreads();
  }
  // ---- Level 3: L2-out -> 8 nodes/tree (1 tile, trees packed) ----
  {
    f32x4 a0 = bias[0], b0 = bias[1];
    tile16<0>(hb, A, RL3, RR3, a0, b0);
    __syncthreads();
    wtile<0>(hb, W3, a0, b0);
    __syncthreads();
  }
  // ---- Level 4: -> 4 nodes/tree (8 valid cols) ----
  {
    f32x4 a0 = bias[0], b0 = bias[1];
    tile16<0>(hb, A, RL4, RR4, a0, b0);
    __syncthreads();
    if (l15 < 8) wtile<0>(hb, W4, a0, b0);
    __syncthreads();
  }
  // ---- Level 5: -> 2 nodes/tree (4 valid cols) ----
  {
    f32x4 a0 = bias[0], b0 = bias[1];
    tile16<0>(hb, A, RL5, RR5, a0, b0);
    __syncthreads();
    if (l15 < 4) wtile<0>(hb, W5, a0, b0);
    __syncthreads();
  }
  // ---- Level 6: -> root at slot 0 (2 valid cols) ----
  {
    f32x4 a0 = bias[0], b0 = bias[1];
    tile16<0>(hb, A, RL6, RR6, a0, b0);
    __syncthreads();
    if (l15 < 2) wtile<0>(hb, W6, a0, b0);
    __syncthreads();
  }

  // After levels: roots at slot 0 (bytes 0-15/chunk/tree). Slots 32-63 hold
  // dead leaf data. Carve: partial[j] (j<256) at tree0 chunk (j>>4),
  // bytes 512+(j&15)*4; zbuf[i] (i<128) at tree1 chunk (i>>3), bytes 768+(i&7)*4.

  // ---- cpr: 2 threads per output c (one per tree-half of K) ----
  {
    const int half = tid >> 7, c = tid & 127;
    const char* rp = hb + half * 16384;   // root row, slot 0
    float acc = 0.f;
#pragma unroll 4
    for (int ch = 0; ch < 16; ++ch) {
      uint4 u = *(const uint4*)(rp + ch * 1024);   // broadcast within wave
      float2 e0 = up2(u.x), e1 = up2(u.y), e2 = up2(u.z), e3 = up2(u.w);
      if constexpr (PRE) {
        uint4 wq = *(const uint4*)(cpr_bf + c * 256 + half * 128 + ch * 8);
        float2 w0 = up2(wq.x), w1 = up2(wq.y), w2 = up2(wq.z), w3 = up2(wq.w);
        acc += e0.x * w0.x + e0.y * w0.y + e1.x * w1.x + e1.y * w1.y
             + e2.x * w2.x + e2.y * w2.y + e3.x * w3.x + e3.y * w3.y;
      } else {
        const float* wr = cpr_w + c * 256 + half * 128 + ch * 8;
        float4 w0 = *(const float4*)wr, w1 = *(const float4*)(wr + 4);
        acc += e0.x * w0.x + e0.y * w0.y + e1.x * w0.z + e1.y * w0.w
             + e2.x * w1.x + e2.y * w1.y + e3.x * w1.z + e3.y * w1.w;
      }
    }
    *(float*)(hb + ((tid >> 4) << 10) + 512 + ((tid & 15) << 2)) = acc;
  }
  __syncthreads();
  if (tid < 128) {
    const float p0 = *(const float*)(hb + ((tid >> 4) << 10) + 512 + ((tid & 15) << 2));
    const int j1 = tid + 128;
    const float p1 = *(const float*)(hb + ((j1 >> 4) << 10) + 512 + ((j1 & 15) << 2));
    float z = p0 + p1 + cpr_b[tid];
    z = z > 0.f ? z : 0.01f * z;
    *(float*)(hb + 16384 + ((tid >> 3) << 10) + 768 + ((tid & 7) << 2)) = z;
  }
  __syncthreads();

  // ---- softmax head (wave 0) ----
  if (wv == 0) {
    const int i0 = lane, i1 = 64 + lane;
    const float za = *(const float*)(hb + 16384 + ((i0 >> 3) << 10) + 768 + ((i0 & 7) << 2));
    const float zc = *(const float*)(hb + 16384 + ((i1 >> 3) << 10) + 768 + ((i1 & 7) << 2));
    float p[7];
#pragma unroll
    for (int j = 0; j < 7; ++j)
      p[j] = za * sm_w[j * 128 + lane] + zc * sm_w[j * 128 + 64 + lane];
#pragma unroll
    for (int j = 0; j < 7; ++j) {
      float v = p[j];
#pragma unroll
      for (int off = 32; off >= 1; off >>= 1) v += __shfl_xor(v, off, 64);
      p[j] = v + sm_b[j];
    }
    float mx = p[0];
#pragma unroll
    for (int j = 1; j < 7; ++j) mx = fmaxf(mx, p[j]);
    float e[7], s = 0.f;
#pragma unroll
    for (int j = 0; j < 7; ++j) { e[j] = __expf(p[j] - mx); s += e[j]; }
    const float inv = 1.f / s;
    if (lane == 0) {
#pragma unroll
      for (int j = 0; j < 7; ++j) out[b * 7 + j] = e[j] * inv;
    }
  }
}

extern "C" void kernel_launch(void* const* d_in, const int* in_sizes, int n_in,
                              void* d_out, int out_size, void* d_ws, size_t ws_size,
                              hipStream_t stream) {
  const int*   tokens = (const int*)  d_in[0];
  const float* voc_w  = (const float*)d_in[1];
  const float* voc_b  = (const float*)d_in[2];
  const float* cps_w  = (const float*)d_in[3];
  const float* cps_b  = (const float*)d_in[4];
  const float* cpr_w  = (const float*)d_in[5];
  const float* cpr_b  = (const float*)d_in[6];
  const float* sm_w   = (const float*)d_in[7];
  const float* sm_b   = (const float*)d_in[8];
  float* out = (float*)d_out;

  const int B = in_sizes[0] / 128;                     // 8192
  const size_t need = (size_t)(VOCN + CPSN + CPRN) * sizeof(ushort);

  if (ws_size >= need) {
    ushort* ws = (ushort*)d_ws;
    const int tot4 = (VOCN + CPSN + CPRN) / 4;
    prep_kernel<<<(tot4 + 255) / 256, 256, 0, stream>>>(voc_w, voc_b, cps_w, cpr_w, ws);
    trnn_kernel<1><<<B, 256, 0, stream>>>(tokens, voc_w, voc_b, cps_w, cps_b,
                                          cpr_w, cpr_b, sm_w, sm_b, ws, out);
  } else {
    trnn_kernel<0><<<B, 256, 0, stream>>>(tokens, voc_w, voc_b, cps_w, cps_b,
                                          cpr_w, cpr_b, sm_w, sm_b,
                                          (const ushort*)d_ws, out);
  }
}